// Round 16
// baseline (16104.997 us; speedup 1.0000x reference)
//
#include <hip/hip_runtime.h>
#include <hip/hip_bf16.h>
#include <hip/hip_cooperative_groups.h>
#include <math.h>

namespace cg = cooperative_groups;

// B=64, S=512, D=768, H=384 (4H=1536), T=9. All fp32; output int32 tags [B,S].
//
// r16: r15 (12.4ms) + scan inner-loop pipelining ONLY:
//  - xg for step t+1 prefetched into registers during step t's MAC (L3 latency
//    off the critical path; previously acc was INITIALIZED from the xg loads,
//    putting ~600cy of L3 latency at the head of the FMA chain).
//  - MAC accumulates into zero-init regs; xg added at gsm-write (also matches
//    the reference's g_t + h@Whh^T association order).
//  - k-loop unroll 8 (more outstanding L2 loads).
// Structure unchanged: 32 block-local scan chains (same-dir-per-XCD, WT slice
// L2-resident), 224 producers fill 64-step xg windows, 9 grid.syncs.
//
// ws main: [0,WT) WT[2][384][1536]; [WT,+XGW) xg window dbuf; [WT+XGW,+HS) hs.
// h1/em reuse dead xgw region after the fused kernel.

#define NB 64
#define NS 512
#define ND 768
#define NH 384
#define NG 1536
#define NT 9

#define WT_BYTES   4718592ull                 // 2*384*1536*4
#define XGWIN_FL   12582912ull                // floats per window buffer (50.33MB)
#define XGW_BYTES  (2ull * XGWIN_FL * 4ull)   // 100,663,296
#define HS_BYTES   100663296ull               // 2*512*64*384*4
#define MAIN_NEED  (WT_BYTES + XGW_BYTES + HS_BYTES)   // 206,045,184

#define XGF_BYTES  402653184ull               // fallback full xg basis

__device__ inline float sigm(float x) { return 1.f / (1.f + expf(-x)); }

// ---------------- K0: transpose Whh[1536][384] -> WT[dir][384][1536] ---------------
__global__ __launch_bounds__(256) void transpose_whh(
    const float* __restrict__ WhhF, const float* __restrict__ WhhB,
    float* __restrict__ WT)
{
    __shared__ float tile[32][33];
    const int dirn = blockIdx.z;
    const float* W = dirn ? WhhB : WhhF;
    const int r0 = blockIdx.x * 32;   // gate-row tile, 0..1535
    const int k0 = blockIdx.y * 32;   // k tile, 0..383
    const int tx = threadIdx.x & 31, ty = threadIdx.x >> 5;
    for (int i = ty; i < 32; i += 8)
        tile[i][tx] = W[(size_t)(r0 + i) * NH + k0 + tx];
    __syncthreads();
    float* O = WT + (size_t)dirn * NH * NG;
    for (int i = ty; i < 32; i += 8)
        O[(size_t)(k0 + i) * NG + r0 + tx] = tile[tx][i];
}

// ---------------- fused: 32 block-local scan chains + 224 xg producers -------------
__global__ __launch_bounds__(384, 1) void fused_scan(
    const float* __restrict__ X,
    const float* __restrict__ WihF, const float* __restrict__ WihB,
    const float* __restrict__ bihF, const float* __restrict__ bhhF,
    const float* __restrict__ bihB, const float* __restrict__ bhhB,
    const float* __restrict__ WT, float* __restrict__ xgw,
    float* __restrict__ hs)
{
    cg::grid_group grid = cg::this_grid();
    const int bid = blockIdx.x, tid = threadIdx.x;

    __shared__ __align__(16) float As[16][132];
    __shared__ __align__(16) float Bs[16][68];
    __shared__ __align__(16) float hc[4 * 384];    // h[t-1] for 4 batches
    __shared__ __align__(16) float gsm[4 * 1536];  // gate preacts

    // ---- producer: compute xg window W into xgw[(W&1)] over tiles [pb::nb] ----
    auto produce = [&](int W, int nb, int pb) {
        float* dst = xgw + (size_t)(W & 1) * XGWIN_FL;
        const int la_r = tid >> 1, la_k = (tid & 1) * 8;
        const int lb_n = tid >> 2, lb_k = (tid & 3) * 4;
        const int ty = tid >> 4, tx = tid & 15;
        for (int tile = pb; tile < 1536; tile += nb) {
            const int mt = tile / 24, nt = tile - mt * 24;
            const int m0 = mt * 128, n0 = nt * 64;
            const int dirT = m0 >> 12;
            const float* Wih = dirT ? WihB : WihF;
            const float* bih = dirT ? bihB : bihF;
            const float* bhh = dirT ? bhhB : bhhF;
            const float* Aptr = nullptr;
            const float* Bptr = nullptr;
            if (tid < 256) {
                int m = m0 + la_r;
                int rem = m & 4095, b = rem >> 6, tl = rem & 63;
                int gt = W * 64 + tl;
                int xrow = b * 512 + (dirT ? (511 - gt) : gt);
                Aptr = X + (size_t)xrow * ND + la_k;
                Bptr = Wih + (size_t)(n0 + lb_n) * ND + lb_k;
            }
            float acc[8][4];
#pragma unroll
            for (int i = 0; i < 8; i++)
#pragma unroll
                for (int j = 0; j < 4; j++) acc[i][j] = 0.f;

            for (int k0 = 0; k0 < ND; k0 += 16) {
                float4 av0, av1, bv;
                if (tid < 256) {
                    av0 = *(const float4*)(Aptr + k0);
                    av1 = *(const float4*)(Aptr + k0 + 4);
                    bv = *(const float4*)(Bptr + k0);
                }
                __syncthreads();
                if (tid < 256) {
                    As[la_k + 0][la_r] = av0.x; As[la_k + 1][la_r] = av0.y;
                    As[la_k + 2][la_r] = av0.z; As[la_k + 3][la_r] = av0.w;
                    As[la_k + 4][la_r] = av1.x; As[la_k + 5][la_r] = av1.y;
                    As[la_k + 6][la_r] = av1.z; As[la_k + 7][la_r] = av1.w;
                    Bs[lb_k + 0][lb_n] = bv.x; Bs[lb_k + 1][lb_n] = bv.y;
                    Bs[lb_k + 2][lb_n] = bv.z; Bs[lb_k + 3][lb_n] = bv.w;
                }
                __syncthreads();
                if (tid < 256) {
#pragma unroll
                    for (int kk = 0; kk < 16; kk++) {
                        float4 a0 = *(const float4*)&As[kk][ty * 8];
                        float4 a1 = *(const float4*)&As[kk][ty * 8 + 4];
                        float4 b4 = *(const float4*)&Bs[kk][tx * 4];
                        float av[8] = {a0.x, a0.y, a0.z, a0.w, a1.x, a1.y, a1.z, a1.w};
                        float bw[4] = {b4.x, b4.y, b4.z, b4.w};
#pragma unroll
                        for (int i = 0; i < 8; i++)
#pragma unroll
                            for (int j = 0; j < 4; j++) acc[i][j] += av[i] * bw[j];
                    }
                }
            }
            if (tid < 256) {
                float bias[4];
#pragma unroll
                for (int j = 0; j < 4; j++)
                    bias[j] = bih[n0 + tx * 4 + j] + bhh[n0 + tx * 4 + j];
#pragma unroll
                for (int i = 0; i < 8; i++) {
                    int mm = m0 + ty * 8 + i;
                    int rem2 = mm & 4095, bb = rem2 >> 6, tl2 = rem2 & 63;
                    float4 o;
                    o.x = acc[i][0] + bias[0]; o.y = acc[i][1] + bias[1];
                    o.z = acc[i][2] + bias[2]; o.w = acc[i][3] + bias[3];
                    *(float4*)&dst[(((size_t)dirT * 64 + bb) * 64 + tl2) * NG
                                   + n0 + tx * 4] = o;
                }
            }
            __syncthreads();
        }
    };

    // ---- scan identity (same-dir per XCD): x=bid&7 -> XCD; dir=x>>2 ----
    const bool is_scan = (bid < 32);
    const int xq = bid & 7, sq = bid >> 3;
    const int dir = xq >> 2;
    const int b0 = ((xq & 3) * 4 + sq) * 4;        // batch base (bijective)
    const float4* wt4 = (const float4*)(WT + (size_t)dir * NH * NG);
    float* hsd = hs + (size_t)dir * 512 * 64 * NH;

    float cc0 = 0.f, cc1 = 0.f, cc2 = 0.f, cc3 = 0.f;

    produce(0, 256, bid);
    grid.sync();

#define MACB(A, H) { \
    A.x += (H).x*w0.x; A.y += (H).x*w0.y; A.z += (H).x*w0.z; A.w += (H).x*w0.w; \
    A.x += (H).y*w1.x; A.y += (H).y*w1.y; A.z += (H).y*w1.z; A.w += (H).y*w1.w; \
    A.x += (H).z*w2.x; A.y += (H).z*w2.y; A.z += (H).z*w2.z; A.w += (H).z*w2.w; \
    A.x += (H).w*w3.x; A.y += (H).w*w3.y; A.z += (H).w*w3.z; A.w += (H).w*w3.w; }

    for (int w = 0; w < 8; ++w) {
        if (is_scan) {
            const float* xgwin = xgw + (size_t)(w & 1) * XGWIN_FL;
            // prefetch xg for tl=0
            float4 xn0 = *(const float4*)&xgwin[
                (((size_t)(dir * 64 + b0 + 0)) * 64 + 0) * NG + 4 * tid];
            float4 xn1 = *(const float4*)&xgwin[
                (((size_t)(dir * 64 + b0 + 1)) * 64 + 0) * NG + 4 * tid];
            float4 xn2 = *(const float4*)&xgwin[
                (((size_t)(dir * 64 + b0 + 2)) * 64 + 0) * NG + 4 * tid];
            float4 xn3 = *(const float4*)&xgwin[
                (((size_t)(dir * 64 + b0 + 3)) * 64 + 0) * NG + 4 * tid];
            for (int tl = 0; tl < 64; ++tl) {
                const int t = w * 64 + tl;
                // consume prefetched xg; issue next step's loads (hidden by MAC)
                float4 xc0 = xn0, xc1 = xn1, xc2 = xn2, xc3 = xn3;
                if (tl < 63) {
                    xn0 = *(const float4*)&xgwin[
                        (((size_t)(dir * 64 + b0 + 0)) * 64 + tl + 1) * NG + 4 * tid];
                    xn1 = *(const float4*)&xgwin[
                        (((size_t)(dir * 64 + b0 + 1)) * 64 + tl + 1) * NG + 4 * tid];
                    xn2 = *(const float4*)&xgwin[
                        (((size_t)(dir * 64 + b0 + 2)) * 64 + tl + 1) * NG + 4 * tid];
                    xn3 = *(const float4*)&xgwin[
                        (((size_t)(dir * 64 + b0 + 3)) * 64 + tl + 1) * NG + 4 * tid];
                }
                float4 acc0 = {0.f, 0.f, 0.f, 0.f};
                float4 acc1 = {0.f, 0.f, 0.f, 0.f};
                float4 acc2 = {0.f, 0.f, 0.f, 0.f};
                float4 acc3 = {0.f, 0.f, 0.f, 0.f};
                if (t > 0) {
#pragma unroll 8
                    for (int k4 = 0; k4 < 96; ++k4) {
                        const float4* wk = wt4 + (size_t)(k4 * 4) * 384 + tid;
                        float4 w0 = wk[0];
                        float4 w1 = wk[384];
                        float4 w2 = wk[768];
                        float4 w3 = wk[1152];
                        float4 h0 = *(const float4*)&hc[0 * 384 + k4 * 4];
                        float4 h1 = *(const float4*)&hc[1 * 384 + k4 * 4];
                        float4 h2 = *(const float4*)&hc[2 * 384 + k4 * 4];
                        float4 h3 = *(const float4*)&hc[3 * 384 + k4 * 4];
                        MACB(acc0, h0)
                        MACB(acc1, h1)
                        MACB(acc2, h2)
                        MACB(acc3, h3)
                    }
                }
                // add xg at the end (matches reference g_t + h@Whh^T order)
                acc0.x += xc0.x; acc0.y += xc0.y; acc0.z += xc0.z; acc0.w += xc0.w;
                acc1.x += xc1.x; acc1.y += xc1.y; acc1.z += xc1.z; acc1.w += xc1.w;
                acc2.x += xc2.x; acc2.y += xc2.y; acc2.z += xc2.z; acc2.w += xc2.w;
                acc3.x += xc3.x; acc3.y += xc3.y; acc3.z += xc3.z; acc3.w += xc3.w;
                *(float4*)&gsm[0 * 1536 + 4 * tid] = acc0;
                *(float4*)&gsm[1 * 1536 + 4 * tid] = acc1;
                *(float4*)&gsm[2 * 1536 + 4 * tid] = acc2;
                *(float4*)&gsm[3 * 1536 + 4 * tid] = acc3;
                __syncthreads();
#define CELL(BB, CC) { \
                float iv = gsm[(BB) * 1536 + tid]; \
                float fv = gsm[(BB) * 1536 + 384 + tid]; \
                float gg = gsm[(BB) * 1536 + 768 + tid]; \
                float ov = gsm[(BB) * 1536 + 1152 + tid]; \
                float c = (t == 0) ? 0.f : CC; \
                float si = sigm(iv), sf = sigm(fv), so = sigm(ov); \
                c = sf * c + si * tanhf(gg); \
                CC = c; \
                float h = so * tanhf(c); \
                hc[(BB) * 384 + tid] = h; \
                hsd[((size_t)t * 64 + b0 + (BB)) * NH + tid] = h; }
                CELL(0, cc0) CELL(1, cc1) CELL(2, cc2) CELL(3, cc3)
#undef CELL
                __syncthreads();
            }
        } else if (w < 7) {
            produce(w + 1, 224, bid - 32);
        }
        grid.sync();
    }
#undef MACB
}

// ======================= FALLBACK PATH (r7, proven) ================================
__global__ __launch_bounds__(256) void gemm_xg(
    const float* __restrict__ X,
    const float* __restrict__ WihF, const float* __restrict__ WihB,
    const float* __restrict__ bihF, const float* __restrict__ bhhF,
    const float* __restrict__ bihB, const float* __restrict__ bhhB,
    float* __restrict__ xg, int b_base, int mrows)
{
    const int dir = blockIdx.z;
    const int m0 = blockIdx.x * 128;
    const int n0 = blockIdx.y * 64;
    const float* Wih = dir ? WihB : WihF;
    const float* bih = dir ? bihB : bihF;
    const float* bhh = dir ? bhhB : bhhF;
    __shared__ __align__(16) float As[16][132];
    __shared__ __align__(16) float Bs[16][68];
    const int tid = threadIdx.x;
    const int la_r = tid >> 1, la_k = (tid & 1) * 8;
    int mm = m0 + la_r;
    int bl = mm >> 9, s = mm & 511;
    int bglob = b_base + bl;
    int xrow = dir ? (bglob * 512 + (511 - s)) : (bglob * 512 + s);
    const float* Aptr = X + (size_t)xrow * ND + la_k;
    const int lb_n = tid >> 2, lb_k = (tid & 3) * 4;
    const float* Bptr = Wih + (size_t)(n0 + lb_n) * ND + lb_k;
    const int ty = tid >> 4, tx = tid & 15;
    float acc[8][4];
#pragma unroll
    for (int i = 0; i < 8; i++)
#pragma unroll
        for (int j = 0; j < 4; j++) acc[i][j] = 0.f;
    for (int k0 = 0; k0 < ND; k0 += 16) {
        float4 av0 = *(const float4*)(Aptr + k0);
        float4 av1 = *(const float4*)(Aptr + k0 + 4);
        float4 bv = *(const float4*)(Bptr + k0);
        __syncthreads();
        As[la_k + 0][la_r] = av0.x; As[la_k + 1][la_r] = av0.y;
        As[la_k + 2][la_r] = av0.z; As[la_k + 3][la_r] = av0.w;
        As[la_k + 4][la_r] = av1.x; As[la_k + 5][la_r] = av1.y;
        As[la_k + 6][la_r] = av1.z; As[la_k + 7][la_r] = av1.w;
        Bs[lb_k + 0][lb_n] = bv.x; Bs[lb_k + 1][lb_n] = bv.y;
        Bs[lb_k + 2][lb_n] = bv.z; Bs[lb_k + 3][lb_n] = bv.w;
        __syncthreads();
#pragma unroll
        for (int kk = 0; kk < 16; kk++) {
            float4 a0 = *(const float4*)&As[kk][ty * 8];
            float4 a1 = *(const float4*)&As[kk][ty * 8 + 4];
            float4 b4 = *(const float4*)&Bs[kk][tx * 4];
            float av[8] = {a0.x, a0.y, a0.z, a0.w, a1.x, a1.y, a1.z, a1.w};
            float bw[4] = {b4.x, b4.y, b4.z, b4.w};
#pragma unroll
            for (int i = 0; i < 8; i++)
#pragma unroll
                for (int j = 0; j < 4; j++) acc[i][j] += av[i] * bw[j];
        }
    }
    float bias[4];
#pragma unroll
    for (int j = 0; j < 4; j++) bias[j] = bih[n0 + tx * 4 + j] + bhh[n0 + tx * 4 + j];
#pragma unroll
    for (int i = 0; i < 8; i++) {
        int m = m0 + ty * 8 + i;
        float4 o;
        o.x = acc[i][0] + bias[0]; o.y = acc[i][1] + bias[1];
        o.z = acc[i][2] + bias[2]; o.w = acc[i][3] + bias[3];
        *(float4*)&xg[((size_t)dir * mrows + m) * NG + n0 + tx * 4] = o;
    }
}

__global__ __launch_bounds__(384) void lstm_seq(
    const float* __restrict__ xg, const float* __restrict__ WT,
    float* __restrict__ hs, int b_base, int Bc, int mrows)
{
    const int bid = blockIdx.x;
    const int xcd = bid & 7, slot = bid >> 3;
    const int dir = xcd >> 2;
    const int bl = (xcd & 3) * (Bc >> 2) + slot;
    const int tid = threadIdx.x;
    __shared__ __align__(16) float hc[384];
    __shared__ float cstS[384];
    __shared__ __align__(16) float gsm[1536];
    const float4* wt4 = (const float4*)(WT + (size_t)dir * NH * NG);
    const float4* xg4 = (const float4*)(xg + ((size_t)dir * mrows + (size_t)bl * 512) * NG);
    float* hsd = hs + (size_t)dir * 512 * 64 * NH + (size_t)(b_base + bl) * NH;
    for (int t = 0; t < 512; ++t) {
        float4 acc = xg4[(size_t)t * 384 + tid];
        if (t > 0) {
#pragma unroll 4
            for (int k4 = 0; k4 < 96; ++k4) {
                float4 h4 = *(const float4*)&hc[k4 * 4];
                const float4* wk = wt4 + (size_t)(k4 * 4) * 384 + tid;
                float4 w0 = wk[0];
                float4 w1 = wk[384];
                float4 w2 = wk[768];
                float4 w3 = wk[1152];
                acc.x += h4.x * w0.x; acc.y += h4.x * w0.y;
                acc.z += h4.x * w0.z; acc.w += h4.x * w0.w;
                acc.x += h4.y * w1.x; acc.y += h4.y * w1.y;
                acc.z += h4.y * w1.z; acc.w += h4.y * w1.w;
                acc.x += h4.z * w2.x; acc.y += h4.z * w2.y;
                acc.z += h4.z * w2.z; acc.w += h4.z * w2.w;
                acc.x += h4.w * w3.x; acc.y += h4.w * w3.y;
                acc.z += h4.w * w3.z; acc.w += h4.w * w3.w;
            }
        }
        *(float4*)&gsm[tid * 4] = acc;
        __syncthreads();
        float iv = gsm[tid];
        float fv = gsm[384 + tid];
        float gv = gsm[768 + tid];
        float ov = gsm[1152 + tid];
        float c = (t == 0) ? 0.f : cstS[tid];
        float si = sigm(iv), sf = sigm(fv), so = sigm(ov);
        c = sf * c + si * tanhf(gv);
        cstS[tid] = c;
        float h = so * tanhf(c);
        hc[tid] = h;
        hsd[(size_t)t * 64 * NH + tid] = h;
        __syncthreads();
    }
}

// ---------------- tail kernels -----------------------------------------------------
__global__ __launch_bounds__(256) void gemm_h1(
    const float* __restrict__ hs, const float* __restrict__ W1,
    const float* __restrict__ b1, float* __restrict__ h1)
{
    const int m0 = blockIdx.x * 128;
    const int n0 = blockIdx.y * 64;
    __shared__ __align__(16) float As[16][132];
    __shared__ __align__(16) float Bs[16][68];
    const int tid = threadIdx.x;
    const int la_r = tid >> 1, la_k = (tid & 1) * 8;
    int mm = m0 + la_r;
    int b = mm >> 9, s = mm & 511;
    const float* Af = hs + ((size_t)s * 64 + b) * NH;
    const float* Ab = hs + ((size_t)(1023 - s) * 64 + b) * NH - NH;
    const int lb_n = tid >> 2, lb_k = (tid & 3) * 4;
    const float* Bptr = W1 + (size_t)(n0 + lb_n) * ND + lb_k;
    const int ty = tid >> 4, tx = tid & 15;
    float acc[8][4];
#pragma unroll
    for (int i = 0; i < 8; i++)
#pragma unroll
        for (int j = 0; j < 4; j++) acc[i][j] = 0.f;
    for (int k0 = 0; k0 < ND; k0 += 16) {
        int k = k0 + la_k;
        const float* src = (k < NH) ? Af : Ab;
        float4 av0 = *(const float4*)(src + k);
        float4 av1 = *(const float4*)(src + k + 4);
        float4 bv = *(const float4*)(Bptr + k0);
        __syncthreads();
        As[la_k + 0][la_r] = av0.x; As[la_k + 1][la_r] = av0.y;
        As[la_k + 2][la_r] = av0.z; As[la_k + 3][la_r] = av0.w;
        As[la_k + 4][la_r] = av1.x; As[la_k + 5][la_r] = av1.y;
        As[la_k + 6][la_r] = av1.z; As[la_k + 7][la_r] = av1.w;
        Bs[lb_k + 0][lb_n] = bv.x; Bs[lb_k + 1][lb_n] = bv.y;
        Bs[lb_k + 2][lb_n] = bv.z; Bs[lb_k + 3][lb_n] = bv.w;
        __syncthreads();
#pragma unroll
        for (int kk = 0; kk < 16; kk++) {
            float4 a0 = *(const float4*)&As[kk][ty * 8];
            float4 a1 = *(const float4*)&As[kk][ty * 8 + 4];
            float4 b4 = *(const float4*)&Bs[kk][tx * 4];
            float av[8] = {a0.x, a0.y, a0.z, a0.w, a1.x, a1.y, a1.z, a1.w};
            float bw[4] = {b4.x, b4.y, b4.z, b4.w};
#pragma unroll
            for (int i = 0; i < 8; i++)
#pragma unroll
                for (int j = 0; j < 4; j++) acc[i][j] += av[i] * bw[j];
        }
    }
    float bias[4];
#pragma unroll
    for (int j = 0; j < 4; j++) bias[j] = b1[n0 + tx * 4 + j];
#pragma unroll
    for (int i = 0; i < 8; i++) {
        int m = m0 + ty * 8 + i;
        float4 o;
        o.x = acc[i][0] + bias[0]; o.y = acc[i][1] + bias[1];
        o.z = acc[i][2] + bias[2]; o.w = acc[i][3] + bias[3];
        *(float4*)&h1[(size_t)m * 256 + n0 + tx * 4] = o;
    }
}

__global__ __launch_bounds__(256) void mlp_em(
    const float* __restrict__ h1, const float* __restrict__ W2,
    const float* __restrict__ b2, const float* __restrict__ Wc,
    const float* __restrict__ bc, float* __restrict__ em)
{
    __shared__ __align__(16) float As[32][68];
    __shared__ __align__(16) float Bs[32][132];
    __shared__ __align__(16) float h2s[64][132];
    __shared__ __align__(16) float wcs[9][128];
    __shared__ float bcs[9];
    const int tid = threadIdx.x;
    const int m0 = blockIdx.x * 64;
    const int la_r = tid >> 2, la_k = (tid & 3) * 8;
    const float* Aptr = h1 + (size_t)(m0 + la_r) * 256 + la_k;
    const int lb_n = tid >> 1, lb_k = (tid & 1) * 16;
    const float* Bptr = W2 + (size_t)lb_n * 256 + lb_k;
    const int ty = tid >> 4, tx = tid & 15;
    float acc[4][8];
#pragma unroll
    for (int i = 0; i < 4; i++)
#pragma unroll
        for (int j = 0; j < 8; j++) acc[i][j] = 0.f;
    for (int k0 = 0; k0 < 256; k0 += 32) {
        float4 av0 = *(const float4*)(Aptr + k0);
        float4 av1 = *(const float4*)(Aptr + k0 + 4);
        float4 bv0 = *(const float4*)(Bptr + k0);
        float4 bv1 = *(const float4*)(Bptr + k0 + 4);
        float4 bv2 = *(const float4*)(Bptr + k0 + 8);
        float4 bv3 = *(const float4*)(Bptr + k0 + 12);
        __syncthreads();
        As[la_k + 0][la_r] = av0.x; As[la_k + 1][la_r] = av0.y;
        As[la_k + 2][la_r] = av0.z; As[la_k + 3][la_r] = av0.w;
        As[la_k + 4][la_r] = av1.x; As[la_k + 5][la_r] = av1.y;
        As[la_k + 6][la_r] = av1.z; As[la_k + 7][la_r] = av1.w;
        Bs[lb_k + 0][lb_n] = bv0.x; Bs[lb_k + 1][lb_n] = bv0.y;
        Bs[lb_k + 2][lb_n] = bv0.z; Bs[lb_k + 3][lb_n] = bv0.w;
        Bs[lb_k + 4][lb_n] = bv1.x; Bs[lb_k + 5][lb_n] = bv1.y;
        Bs[lb_k + 6][lb_n] = bv1.z; Bs[lb_k + 7][lb_n] = bv1.w;
        Bs[lb_k + 8][lb_n] = bv2.x; Bs[lb_k + 9][lb_n] = bv2.y;
        Bs[lb_k + 10][lb_n] = bv2.z; Bs[lb_k + 11][lb_n] = bv2.w;
        Bs[lb_k + 12][lb_n] = bv3.x; Bs[lb_k + 13][lb_n] = bv3.y;
        Bs[lb_k + 14][lb_n] = bv3.z; Bs[lb_k + 15][lb_n] = bv3.w;
        __syncthreads();
#pragma unroll
        for (int kk = 0; kk < 32; kk++) {
            float4 a4 = *(const float4*)&As[kk][ty * 4];
            float4 b40 = *(const float4*)&Bs[kk][tx * 8];
            float4 b41 = *(const float4*)&Bs[kk][tx * 8 + 4];
            float av[4] = {a4.x, a4.y, a4.z, a4.w};
            float bw[8] = {b40.x, b40.y, b40.z, b40.w, b41.x, b41.y, b41.z, b41.w};
#pragma unroll
            for (int i = 0; i < 4; i++)
#pragma unroll
                for (int j = 0; j < 8; j++) acc[i][j] += av[i] * bw[j];
        }
    }
    __syncthreads();
#pragma unroll
    for (int j = 0; j < 8; j++) {
        float bb = b2[tx * 8 + j];
#pragma unroll
        for (int i = 0; i < 4; i++) h2s[ty * 4 + i][tx * 8 + j] = acc[i][j] + bb;
    }
    for (int idx = tid; idx < 9 * 128; idx += 256) wcs[idx / 128][idx & 127] = Wc[idx];
    if (tid < 9) bcs[tid] = bc[tid];
    __syncthreads();
    const int r = tid & 63, tg0 = tid >> 6;
    for (int tag = tg0; tag < 9; tag += 4) {
        float s0 = 0, s1 = 0, s2 = 0, s3 = 0;
#pragma unroll
        for (int kk = 0; kk < 32; kk++) {
            float4 hv = *(const float4*)&h2s[r][kk * 4];
            float4 wv = *(const float4*)&wcs[tag][kk * 4];
            s0 += hv.x * wv.x; s1 += hv.y * wv.y;
            s2 += hv.z * wv.z; s3 += hv.w * wv.w;
        }
        em[(size_t)(m0 + r) * NT + tag] = (s0 + s1) + (s2 + s3) + bcs[tag];
    }
}

__global__ __launch_bounds__(64) void viterbi(
    const float* __restrict__ em, const float* __restrict__ startT,
    const float* __restrict__ endT, const float* __restrict__ trans,
    int* __restrict__ out)
{
    const int b = blockIdx.x, j = threadIdx.x;
    __shared__ int hist[511][9];
    __shared__ int tags[512];
    const float* E = em + (size_t)b * 512 * NT;
    const int jj = (j < 9) ? j : 0;
    float sc[9], tc[9];
#pragma unroll
    for (int i = 0; i < 9; i++) sc[i] = startT[i] + E[i];
#pragma unroll
    for (int i = 0; i < 9; i++) tc[i] = trans[i * 9 + jj];
    float e_cur = E[9 + jj];
    for (int s = 1; s < 512; ++s) {
        float e_nxt = (s < 511) ? E[(size_t)(s + 1) * 9 + jj] : 0.f;
        float best = -3.0e38f;
        int bi = 0;
#pragma unroll
        for (int i = 0; i < 9; i++) {
            float v = (sc[i] + tc[i]) + e_cur;
            if (v > best) { best = v; bi = i; }
        }
        if (j < 9) hist[s - 1][j] = bi;
#pragma unroll
        for (int i = 0; i < 9; i++) sc[i] = __shfl(best, i);
        e_cur = e_nxt;
    }
    __syncthreads();
#pragma unroll
    for (int i = 0; i < 9; i++) sc[i] += endT[i];
    float best = -3.0e38f;
    int last = 0;
#pragma unroll
    for (int i = 0; i < 9; i++)
        if (sc[i] > best) { best = sc[i]; last = i; }
    if (j == 0) {
        tags[511] = last;
        int tg = last;
        for (int s = 510; s >= 0; --s) { tg = hist[s][tg]; tags[s] = tg; }
    }
    __syncthreads();
    for (int s = j; s < 512; s += 64) out[(size_t)b * 512 + s] = tags[s];
}

__global__ void fill_out(int* out, int n, int v)
{
    int i = blockIdx.x * 256 + threadIdx.x;
    if (i < n) out[i] = v;
}

// -----------------------------------------------------------------------------------
extern "C" void kernel_launch(void* const* d_in, const int* in_sizes, int n_in,
                              void* d_out, int out_size, void* d_ws, size_t ws_size,
                              hipStream_t stream)
{
    const float* bert = (const float*)d_in[0];
    const float* WihF = (const float*)d_in[2];
    const float* WhhF = (const float*)d_in[3];
    const float* bihF = (const float*)d_in[4];
    const float* bhhF = (const float*)d_in[5];
    const float* WihB = (const float*)d_in[6];
    const float* WhhB = (const float*)d_in[7];
    const float* bihB = (const float*)d_in[8];
    const float* bhhB = (const float*)d_in[9];
    const float* W1 = (const float*)d_in[10];
    const float* b1 = (const float*)d_in[11];
    const float* W2 = (const float*)d_in[12];
    const float* b2 = (const float*)d_in[13];
    const float* Wc = (const float*)d_in[14];
    const float* bc = (const float*)d_in[15];
    const float* stT = (const float*)d_in[16];
    const float* enT = (const float*)d_in[17];
    const float* trs = (const float*)d_in[18];
    int* out = (int*)d_out;

    char* ws = (char*)d_ws;
    float* WT = (float*)ws;
    bool main_ok = false;
    float* hs = nullptr;
    float* h1 = nullptr;
    float* em = nullptr;

    if (ws_size >= MAIN_NEED) {
        float* xgw = (float*)(ws + WT_BYTES);
        hs = (float*)(ws + WT_BYTES + XGW_BYTES);
        h1 = (float*)(ws + WT_BYTES);
        em = (float*)(ws + WT_BYTES + 33554432ull);

        transpose_whh<<<dim3(48, 12, 2), 256, 0, stream>>>(WhhF, WhhB, WT);

        void* args[] = { (void*)&bert, (void*)&WihF, (void*)&WihB,
                         (void*)&bihF, (void*)&bhhF, (void*)&bihB, (void*)&bhhB,
                         (void*)&WT, (void*)&xgw, (void*)&hs };
        hipError_t e = hipLaunchCooperativeKernel(
            (void*)fused_scan, dim3(256), dim3(384), args, 0, stream);
        if (e == hipSuccess) {
            main_ok = true;
        } else {
            (void)hipGetLastError();
        }
    }

    if (!main_ok) {
        int c = 0;
        for (int cc = 2; cc <= 8; cc *= 2) {
            if (ws_size >= WT_BYTES + XGF_BYTES / cc + HS_BYTES) { c = cc; break; }
        }
        if (c == 0) {
            fill_out<<<dim3((out_size + 255) / 256), 256, 0, stream>>>(
                out, out_size, (int)(ws_size >> 20));
            return;
        }
        float* xg = (float*)(ws + WT_BYTES);
        hs = (float*)(ws + WT_BYTES + XGF_BYTES / c);
        h1 = (float*)(ws + WT_BYTES);
        em = (float*)(ws + WT_BYTES + 33554432ull);

        transpose_whh<<<dim3(48, 12, 2), 256, 0, stream>>>(WhhF, WhhB, WT);

        const int Bc = NB / c;
        const int mrows = Bc * 512;
        for (int chunk = 0; chunk < c; ++chunk) {
            int b_base = chunk * Bc;
            gemm_xg<<<dim3(mrows / 128, 24, 2), 256, 0, stream>>>(
                bert, WihF, WihB, bihF, bhhF, bihB, bhhB, xg, b_base, mrows);
            lstm_seq<<<dim3(2 * Bc), 384, 0, stream>>>(xg, WT, hs, b_base, Bc, mrows);
        }
    }

    gemm_h1<<<dim3(256, 4), 256, 0, stream>>>(hs, W1, b1, h1);
    mlp_em<<<dim3(512), 256, 0, stream>>>(h1, W2, b2, Wc, bc, em);
    viterbi<<<dim3(64), 64, 0, stream>>>(em, stT, enT, trs, out);
}

// Round 17
// 12367.735 us; speedup vs baseline: 1.3022x; 1.3022x over previous
//
#include <hip/hip_runtime.h>
#include <hip/hip_bf16.h>
#include <hip/hip_cooperative_groups.h>
#include <math.h>

namespace cg = cooperative_groups;

// B=64, S=512, D=768, H=384 (4H=1536), T=9. All fp32; output int32 tags [B,S].
//
// r17 = r15 VERBATIM (proven 12.4ms). r16's deeper unroll + xg reg-dbuf
// regressed to 16.1ms (over-extended live ranges serialized the weight
// stream); reverted. Design: 32 block-local scan chains (same-dir-per-XCD,
// 2.36MB WT slice L2-resident -> per-CU-port-bound ~24us/step incl. barriers),
// 224 producers fill 64-step xg windows, 9 grid.syncs total. All per-step
// cross-CU sync mechanisms measured >=30us/step and rejected (r4-r14 ledger).
//
// ws main: [0,WT) WT[2][384][1536]; [WT,+XGW) xg window dbuf; [WT+XGW,+HS) hs.
// h1/em reuse dead xgw region after the fused kernel.

#define NB 64
#define NS 512
#define ND 768
#define NH 384
#define NG 1536
#define NT 9

#define WT_BYTES   4718592ull                 // 2*384*1536*4
#define XGWIN_FL   12582912ull                // floats per window buffer (50.33MB)
#define XGW_BYTES  (2ull * XGWIN_FL * 4ull)   // 100,663,296
#define HS_BYTES   100663296ull               // 2*512*64*384*4
#define MAIN_NEED  (WT_BYTES + XGW_BYTES + HS_BYTES)   // 206,045,184

#define XGF_BYTES  402653184ull               // fallback full xg basis

__device__ inline float sigm(float x) { return 1.f / (1.f + expf(-x)); }

// ---------------- K0: transpose Whh[1536][384] -> WT[dir][384][1536] ---------------
__global__ __launch_bounds__(256) void transpose_whh(
    const float* __restrict__ WhhF, const float* __restrict__ WhhB,
    float* __restrict__ WT)
{
    __shared__ float tile[32][33];
    const int dirn = blockIdx.z;
    const float* W = dirn ? WhhB : WhhF;
    const int r0 = blockIdx.x * 32;   // gate-row tile, 0..1535
    const int k0 = blockIdx.y * 32;   // k tile, 0..383
    const int tx = threadIdx.x & 31, ty = threadIdx.x >> 5;
    for (int i = ty; i < 32; i += 8)
        tile[i][tx] = W[(size_t)(r0 + i) * NH + k0 + tx];
    __syncthreads();
    float* O = WT + (size_t)dirn * NH * NG;
    for (int i = ty; i < 32; i += 8)
        O[(size_t)(k0 + i) * NG + r0 + tx] = tile[tx][i];
}

// ---------------- fused: 32 block-local scan chains + 224 xg producers -------------
__global__ __launch_bounds__(384, 1) void fused_scan(
    const float* __restrict__ X,
    const float* __restrict__ WihF, const float* __restrict__ WihB,
    const float* __restrict__ bihF, const float* __restrict__ bhhF,
    const float* __restrict__ bihB, const float* __restrict__ bhhB,
    const float* __restrict__ WT, float* __restrict__ xgw,
    float* __restrict__ hs)
{
    cg::grid_group grid = cg::this_grid();
    const int bid = blockIdx.x, tid = threadIdx.x;

    __shared__ __align__(16) float As[16][132];
    __shared__ __align__(16) float Bs[16][68];
    __shared__ __align__(16) float hc[4 * 384];    // h[t-1] for 4 batches
    __shared__ __align__(16) float gsm[4 * 1536];  // gate preacts

    // ---- producer: compute xg window W into xgw[(W&1)] over tiles [pb::nb] ----
    // (r8-proven; active threads tid<256)
    auto produce = [&](int W, int nb, int pb) {
        float* dst = xgw + (size_t)(W & 1) * XGWIN_FL;
        const int la_r = tid >> 1, la_k = (tid & 1) * 8;
        const int lb_n = tid >> 2, lb_k = (tid & 3) * 4;
        const int ty = tid >> 4, tx = tid & 15;
        for (int tile = pb; tile < 1536; tile += nb) {
            const int mt = tile / 24, nt = tile - mt * 24;
            const int m0 = mt * 128, n0 = nt * 64;
            const int dirT = m0 >> 12;
            const float* Wih = dirT ? WihB : WihF;
            const float* bih = dirT ? bihB : bihF;
            const float* bhh = dirT ? bhhB : bhhF;
            const float* Aptr = nullptr;
            const float* Bptr = nullptr;
            if (tid < 256) {
                int m = m0 + la_r;
                int rem = m & 4095, b = rem >> 6, tl = rem & 63;
                int gt = W * 64 + tl;
                int xrow = b * 512 + (dirT ? (511 - gt) : gt);
                Aptr = X + (size_t)xrow * ND + la_k;
                Bptr = Wih + (size_t)(n0 + lb_n) * ND + lb_k;
            }
            float acc[8][4];
#pragma unroll
            for (int i = 0; i < 8; i++)
#pragma unroll
                for (int j = 0; j < 4; j++) acc[i][j] = 0.f;

            for (int k0 = 0; k0 < ND; k0 += 16) {
                float4 av0, av1, bv;
                if (tid < 256) {
                    av0 = *(const float4*)(Aptr + k0);
                    av1 = *(const float4*)(Aptr + k0 + 4);
                    bv = *(const float4*)(Bptr + k0);
                }
                __syncthreads();
                if (tid < 256) {
                    As[la_k + 0][la_r] = av0.x; As[la_k + 1][la_r] = av0.y;
                    As[la_k + 2][la_r] = av0.z; As[la_k + 3][la_r] = av0.w;
                    As[la_k + 4][la_r] = av1.x; As[la_k + 5][la_r] = av1.y;
                    As[la_k + 6][la_r] = av1.z; As[la_k + 7][la_r] = av1.w;
                    Bs[lb_k + 0][lb_n] = bv.x; Bs[lb_k + 1][lb_n] = bv.y;
                    Bs[lb_k + 2][lb_n] = bv.z; Bs[lb_k + 3][lb_n] = bv.w;
                }
                __syncthreads();
                if (tid < 256) {
#pragma unroll
                    for (int kk = 0; kk < 16; kk++) {
                        float4 a0 = *(const float4*)&As[kk][ty * 8];
                        float4 a1 = *(const float4*)&As[kk][ty * 8 + 4];
                        float4 b4 = *(const float4*)&Bs[kk][tx * 4];
                        float av[8] = {a0.x, a0.y, a0.z, a0.w, a1.x, a1.y, a1.z, a1.w};
                        float bw[4] = {b4.x, b4.y, b4.z, b4.w};
#pragma unroll
                        for (int i = 0; i < 8; i++)
#pragma unroll
                            for (int j = 0; j < 4; j++) acc[i][j] += av[i] * bw[j];
                    }
                }
            }
            if (tid < 256) {
                float bias[4];
#pragma unroll
                for (int j = 0; j < 4; j++)
                    bias[j] = bih[n0 + tx * 4 + j] + bhh[n0 + tx * 4 + j];
#pragma unroll
                for (int i = 0; i < 8; i++) {
                    int mm = m0 + ty * 8 + i;
                    int rem2 = mm & 4095, bb = rem2 >> 6, tl2 = rem2 & 63;
                    float4 o;
                    o.x = acc[i][0] + bias[0]; o.y = acc[i][1] + bias[1];
                    o.z = acc[i][2] + bias[2]; o.w = acc[i][3] + bias[3];
                    *(float4*)&dst[(((size_t)dirT * 64 + bb) * 64 + tl2) * NG
                                   + n0 + tx * 4] = o;
                }
            }
            __syncthreads();
        }
    };

    // ---- scan identity (same-dir per XCD): x=bid&7 -> XCD; dir=x>>2
    //      (XCDs 0-3 dir0, 4-7 dir1); 4 scan blocks per XCD ----
    const bool is_scan = (bid < 32);
    const int xq = bid & 7, sq = bid >> 3;         // sq in 0..3 for scan blocks
    const int dir = xq >> 2;
    const int b0 = ((xq & 3) * 4 + sq) * 4;        // batch base, 0..60 (bijective)
    const float4* wt4 = (const float4*)(WT + (size_t)dir * NH * NG);
    float* hsd = hs + (size_t)dir * 512 * 64 * NH;

    // cell state for this thread's 4 (batch, unit=tid) cells -- registers
    float cc0 = 0.f, cc1 = 0.f, cc2 = 0.f, cc3 = 0.f;

    // prologue: all 256 blocks produce window 0
    produce(0, 256, bid);
    grid.sync();

#define MACB(A, H) { \
    A.x += (H).x*w0.x; A.y += (H).x*w0.y; A.z += (H).x*w0.z; A.w += (H).x*w0.w; \
    A.x += (H).y*w1.x; A.y += (H).y*w1.y; A.z += (H).y*w1.z; A.w += (H).y*w1.w; \
    A.x += (H).z*w2.x; A.y += (H).z*w2.y; A.z += (H).z*w2.z; A.w += (H).z*w2.w; \
    A.x += (H).w*w3.x; A.y += (H).w*w3.y; A.z += (H).w*w3.z; A.w += (H).w*w3.w; }

    for (int w = 0; w < 8; ++w) {
        if (is_scan) {
            const float* xgwin = xgw + (size_t)(w & 1) * XGWIN_FL;
            for (int tl = 0; tl < 64; ++tl) {
                const int t = w * 64 + tl;
                // init gate preacts from xg (one float4 per batch)
                float4 acc0 = *(const float4*)&xgwin[
                    (((size_t)(dir * 64 + b0 + 0)) * 64 + tl) * NG + 4 * tid];
                float4 acc1 = *(const float4*)&xgwin[
                    (((size_t)(dir * 64 + b0 + 1)) * 64 + tl) * NG + 4 * tid];
                float4 acc2 = *(const float4*)&xgwin[
                    (((size_t)(dir * 64 + b0 + 2)) * 64 + tl) * NG + 4 * tid];
                float4 acc3 = *(const float4*)&xgwin[
                    (((size_t)(dir * 64 + b0 + 3)) * 64 + tl) * NG + 4 * tid];
                if (t > 0) {
#pragma unroll 4
                    for (int k4 = 0; k4 < 96; ++k4) {
                        const float4* wk = wt4 + (size_t)(k4 * 4) * 384 + tid;
                        float4 w0 = wk[0];
                        float4 w1 = wk[384];
                        float4 w2 = wk[768];
                        float4 w3 = wk[1152];
                        float4 h0 = *(const float4*)&hc[0 * 384 + k4 * 4];
                        float4 h1 = *(const float4*)&hc[1 * 384 + k4 * 4];
                        float4 h2 = *(const float4*)&hc[2 * 384 + k4 * 4];
                        float4 h3 = *(const float4*)&hc[3 * 384 + k4 * 4];
                        MACB(acc0, h0)
                        MACB(acc1, h1)
                        MACB(acc2, h2)
                        MACB(acc3, h3)
                    }
                }
                *(float4*)&gsm[0 * 1536 + 4 * tid] = acc0;
                *(float4*)&gsm[1 * 1536 + 4 * tid] = acc1;
                *(float4*)&gsm[2 * 1536 + 4 * tid] = acc2;
                *(float4*)&gsm[3 * 1536 + 4 * tid] = acc3;
                __syncthreads();
                // cell update: thread -> unit tid, batches 0..3
#define CELL(BB, CC) { \
                float iv = gsm[(BB) * 1536 + tid]; \
                float fv = gsm[(BB) * 1536 + 384 + tid]; \
                float gg = gsm[(BB) * 1536 + 768 + tid]; \
                float ov = gsm[(BB) * 1536 + 1152 + tid]; \
                float c = (t == 0) ? 0.f : CC; \
                float si = sigm(iv), sf = sigm(fv), so = sigm(ov); \
                c = sf * c + si * tanhf(gg); \
                CC = c; \
                float h = so * tanhf(c); \
                hc[(BB) * 384 + tid] = h; \
                hsd[((size_t)t * 64 + b0 + (BB)) * NH + tid] = h; }
                CELL(0, cc0) CELL(1, cc1) CELL(2, cc2) CELL(3, cc3)
#undef CELL
                __syncthreads();
            }
        } else if (w < 7) {
            produce(w + 1, 224, bid - 32);
        }
        grid.sync();
    }
#undef MACB
}

// ======================= FALLBACK PATH (r7, proven) ================================
__global__ __launch_bounds__(256) void gemm_xg(
    const float* __restrict__ X,
    const float* __restrict__ WihF, const float* __restrict__ WihB,
    const float* __restrict__ bihF, const float* __restrict__ bhhF,
    const float* __restrict__ bihB, const float* __restrict__ bhhB,
    float* __restrict__ xg, int b_base, int mrows)
{
    const int dir = blockIdx.z;
    const int m0 = blockIdx.x * 128;
    const int n0 = blockIdx.y * 64;
    const float* Wih = dir ? WihB : WihF;
    const float* bih = dir ? bihB : bihF;
    const float* bhh = dir ? bhhB : bhhF;
    __shared__ __align__(16) float As[16][132];
    __shared__ __align__(16) float Bs[16][68];
    const int tid = threadIdx.x;
    const int la_r = tid >> 1, la_k = (tid & 1) * 8;
    int mm = m0 + la_r;
    int bl = mm >> 9, s = mm & 511;
    int bglob = b_base + bl;
    int xrow = dir ? (bglob * 512 + (511 - s)) : (bglob * 512 + s);
    const float* Aptr = X + (size_t)xrow * ND + la_k;
    const int lb_n = tid >> 2, lb_k = (tid & 3) * 4;
    const float* Bptr = Wih + (size_t)(n0 + lb_n) * ND + lb_k;
    const int ty = tid >> 4, tx = tid & 15;
    float acc[8][4];
#pragma unroll
    for (int i = 0; i < 8; i++)
#pragma unroll
        for (int j = 0; j < 4; j++) acc[i][j] = 0.f;
    for (int k0 = 0; k0 < ND; k0 += 16) {
        float4 av0 = *(const float4*)(Aptr + k0);
        float4 av1 = *(const float4*)(Aptr + k0 + 4);
        float4 bv = *(const float4*)(Bptr + k0);
        __syncthreads();
        As[la_k + 0][la_r] = av0.x; As[la_k + 1][la_r] = av0.y;
        As[la_k + 2][la_r] = av0.z; As[la_k + 3][la_r] = av0.w;
        As[la_k + 4][la_r] = av1.x; As[la_k + 5][la_r] = av1.y;
        As[la_k + 6][la_r] = av1.z; As[la_k + 7][la_r] = av1.w;
        Bs[lb_k + 0][lb_n] = bv.x; Bs[lb_k + 1][lb_n] = bv.y;
        Bs[lb_k + 2][lb_n] = bv.z; Bs[lb_k + 3][lb_n] = bv.w;
        __syncthreads();
#pragma unroll
        for (int kk = 0; kk < 16; kk++) {
            float4 a0 = *(const float4*)&As[kk][ty * 8];
            float4 a1 = *(const float4*)&As[kk][ty * 8 + 4];
            float4 b4 = *(const float4*)&Bs[kk][tx * 4];
            float av[8] = {a0.x, a0.y, a0.z, a0.w, a1.x, a1.y, a1.z, a1.w};
            float bw[4] = {b4.x, b4.y, b4.z, b4.w};
#pragma unroll
            for (int i = 0; i < 8; i++)
#pragma unroll
                for (int j = 0; j < 4; j++) acc[i][j] += av[i] * bw[j];
        }
    }
    float bias[4];
#pragma unroll
    for (int j = 0; j < 4; j++) bias[j] = bih[n0 + tx * 4 + j] + bhh[n0 + tx * 4 + j];
#pragma unroll
    for (int i = 0; i < 8; i++) {
        int m = m0 + ty * 8 + i;
        float4 o;
        o.x = acc[i][0] + bias[0]; o.y = acc[i][1] + bias[1];
        o.z = acc[i][2] + bias[2]; o.w = acc[i][3] + bias[3];
        *(float4*)&xg[((size_t)dir * mrows + m) * NG + n0 + tx * 4] = o;
    }
}

__global__ __launch_bounds__(384) void lstm_seq(
    const float* __restrict__ xg, const float* __restrict__ WT,
    float* __restrict__ hs, int b_base, int Bc, int mrows)
{
    const int bid = blockIdx.x;
    const int xcd = bid & 7, slot = bid >> 3;
    const int dir = xcd >> 2;
    const int bl = (xcd & 3) * (Bc >> 2) + slot;
    const int tid = threadIdx.x;
    __shared__ __align__(16) float hc[384];
    __shared__ float cstS[384];
    __shared__ __align__(16) float gsm[1536];
    const float4* wt4 = (const float4*)(WT + (size_t)dir * NH * NG);
    const float4* xg4 = (const float4*)(xg + ((size_t)dir * mrows + (size_t)bl * 512) * NG);
    float* hsd = hs + (size_t)dir * 512 * 64 * NH + (size_t)(b_base + bl) * NH;
    for (int t = 0; t < 512; ++t) {
        float4 acc = xg4[(size_t)t * 384 + tid];
        if (t > 0) {
#pragma unroll 4
            for (int k4 = 0; k4 < 96; ++k4) {
                float4 h4 = *(const float4*)&hc[k4 * 4];
                const float4* wk = wt4 + (size_t)(k4 * 4) * 384 + tid;
                float4 w0 = wk[0];
                float4 w1 = wk[384];
                float4 w2 = wk[768];
                float4 w3 = wk[1152];
                acc.x += h4.x * w0.x; acc.y += h4.x * w0.y;
                acc.z += h4.x * w0.z; acc.w += h4.x * w0.w;
                acc.x += h4.y * w1.x; acc.y += h4.y * w1.y;
                acc.z += h4.y * w1.z; acc.w += h4.y * w1.w;
                acc.x += h4.z * w2.x; acc.y += h4.z * w2.y;
                acc.z += h4.z * w2.z; acc.w += h4.z * w2.w;
                acc.x += h4.w * w3.x; acc.y += h4.w * w3.y;
                acc.z += h4.w * w3.z; acc.w += h4.w * w3.w;
            }
        }
        *(float4*)&gsm[tid * 4] = acc;
        __syncthreads();
        float iv = gsm[tid];
        float fv = gsm[384 + tid];
        float gv = gsm[768 + tid];
        float ov = gsm[1152 + tid];
        float c = (t == 0) ? 0.f : cstS[tid];
        float si = sigm(iv), sf = sigm(fv), so = sigm(ov);
        c = sf * c + si * tanhf(gv);
        cstS[tid] = c;
        float h = so * tanhf(c);
        hc[tid] = h;
        hsd[(size_t)t * 64 * NH + tid] = h;
        __syncthreads();
    }
}

// ---------------- tail kernels -----------------------------------------------------
__global__ __launch_bounds__(256) void gemm_h1(
    const float* __restrict__ hs, const float* __restrict__ W1,
    const float* __restrict__ b1, float* __restrict__ h1)
{
    const int m0 = blockIdx.x * 128;
    const int n0 = blockIdx.y * 64;
    __shared__ __align__(16) float As[16][132];
    __shared__ __align__(16) float Bs[16][68];
    const int tid = threadIdx.x;
    const int la_r = tid >> 1, la_k = (tid & 1) * 8;
    int mm = m0 + la_r;
    int b = mm >> 9, s = mm & 511;
    const float* Af = hs + ((size_t)s * 64 + b) * NH;
    const float* Ab = hs + ((size_t)(1023 - s) * 64 + b) * NH - NH;
    const int lb_n = tid >> 2, lb_k = (tid & 3) * 4;
    const float* Bptr = W1 + (size_t)(n0 + lb_n) * ND + lb_k;
    const int ty = tid >> 4, tx = tid & 15;
    float acc[8][4];
#pragma unroll
    for (int i = 0; i < 8; i++)
#pragma unroll
        for (int j = 0; j < 4; j++) acc[i][j] = 0.f;
    for (int k0 = 0; k0 < ND; k0 += 16) {
        int k = k0 + la_k;
        const float* src = (k < NH) ? Af : Ab;
        float4 av0 = *(const float4*)(src + k);
        float4 av1 = *(const float4*)(src + k + 4);
        float4 bv = *(const float4*)(Bptr + k0);
        __syncthreads();
        As[la_k + 0][la_r] = av0.x; As[la_k + 1][la_r] = av0.y;
        As[la_k + 2][la_r] = av0.z; As[la_k + 3][la_r] = av0.w;
        As[la_k + 4][la_r] = av1.x; As[la_k + 5][la_r] = av1.y;
        As[la_k + 6][la_r] = av1.z; As[la_k + 7][la_r] = av1.w;
        Bs[lb_k + 0][lb_n] = bv.x; Bs[lb_k + 1][lb_n] = bv.y;
        Bs[lb_k + 2][lb_n] = bv.z; Bs[lb_k + 3][lb_n] = bv.w;
        __syncthreads();
#pragma unroll
        for (int kk = 0; kk < 16; kk++) {
            float4 a0 = *(const float4*)&As[kk][ty * 8];
            float4 a1 = *(const float4*)&As[kk][ty * 8 + 4];
            float4 b4 = *(const float4*)&Bs[kk][tx * 4];
            float av[8] = {a0.x, a0.y, a0.z, a0.w, a1.x, a1.y, a1.z, a1.w};
            float bw[4] = {b4.x, b4.y, b4.z, b4.w};
#pragma unroll
            for (int i = 0; i < 8; i++)
#pragma unroll
                for (int j = 0; j < 4; j++) acc[i][j] += av[i] * bw[j];
        }
    }
    float bias[4];
#pragma unroll
    for (int j = 0; j < 4; j++) bias[j] = b1[n0 + tx * 4 + j];
#pragma unroll
    for (int i = 0; i < 8; i++) {
        int m = m0 + ty * 8 + i;
        float4 o;
        o.x = acc[i][0] + bias[0]; o.y = acc[i][1] + bias[1];
        o.z = acc[i][2] + bias[2]; o.w = acc[i][3] + bias[3];
        *(float4*)&h1[(size_t)m * 256 + n0 + tx * 4] = o;
    }
}

__global__ __launch_bounds__(256) void mlp_em(
    const float* __restrict__ h1, const float* __restrict__ W2,
    const float* __restrict__ b2, const float* __restrict__ Wc,
    const float* __restrict__ bc, float* __restrict__ em)
{
    __shared__ __align__(16) float As[32][68];
    __shared__ __align__(16) float Bs[32][132];
    __shared__ __align__(16) float h2s[64][132];
    __shared__ __align__(16) float wcs[9][128];
    __shared__ float bcs[9];
    const int tid = threadIdx.x;
    const int m0 = blockIdx.x * 64;
    const int la_r = tid >> 2, la_k = (tid & 3) * 8;
    const float* Aptr = h1 + (size_t)(m0 + la_r) * 256 + la_k;
    const int lb_n = tid >> 1, lb_k = (tid & 1) * 16;
    const float* Bptr = W2 + (size_t)lb_n * 256 + lb_k;
    const int ty = tid >> 4, tx = tid & 15;
    float acc[4][8];
#pragma unroll
    for (int i = 0; i < 4; i++)
#pragma unroll
        for (int j = 0; j < 8; j++) acc[i][j] = 0.f;
    for (int k0 = 0; k0 < 256; k0 += 32) {
        float4 av0 = *(const float4*)(Aptr + k0);
        float4 av1 = *(const float4*)(Aptr + k0 + 4);
        float4 bv0 = *(const float4*)(Bptr + k0);
        float4 bv1 = *(const float4*)(Bptr + k0 + 4);
        float4 bv2 = *(const float4*)(Bptr + k0 + 8);
        float4 bv3 = *(const float4*)(Bptr + k0 + 12);
        __syncthreads();
        As[la_k + 0][la_r] = av0.x; As[la_k + 1][la_r] = av0.y;
        As[la_k + 2][la_r] = av0.z; As[la_k + 3][la_r] = av0.w;
        As[la_k + 4][la_r] = av1.x; As[la_k + 5][la_r] = av1.y;
        As[la_k + 6][la_r] = av1.z; As[la_k + 7][la_r] = av1.w;
        Bs[lb_k + 0][lb_n] = bv0.x; Bs[lb_k + 1][lb_n] = bv0.y;
        Bs[lb_k + 2][lb_n] = bv0.z; Bs[lb_k + 3][lb_n] = bv0.w;
        Bs[lb_k + 4][lb_n] = bv1.x; Bs[lb_k + 5][lb_n] = bv1.y;
        Bs[lb_k + 6][lb_n] = bv1.z; Bs[lb_k + 7][lb_n] = bv1.w;
        Bs[lb_k + 8][lb_n] = bv2.x; Bs[lb_k + 9][lb_n] = bv2.y;
        Bs[lb_k + 10][lb_n] = bv2.z; Bs[lb_k + 11][lb_n] = bv2.w;
        Bs[lb_k + 12][lb_n] = bv3.x; Bs[lb_k + 13][lb_n] = bv3.y;
        Bs[lb_k + 14][lb_n] = bv3.z; Bs[lb_k + 15][lb_n] = bv3.w;
        __syncthreads();
#pragma unroll
        for (int kk = 0; kk < 32; kk++) {
            float4 a4 = *(const float4*)&As[kk][ty * 4];
            float4 b40 = *(const float4*)&Bs[kk][tx * 8];
            float4 b41 = *(const float4*)&Bs[kk][tx * 8 + 4];
            float av[4] = {a4.x, a4.y, a4.z, a4.w};
            float bw[8] = {b40.x, b40.y, b40.z, b40.w, b41.x, b41.y, b41.z, b41.w};
#pragma unroll
            for (int i = 0; i < 4; i++)
#pragma unroll
                for (int j = 0; j < 8; j++) acc[i][j] += av[i] * bw[j];
        }
    }
    __syncthreads();
#pragma unroll
    for (int j = 0; j < 8; j++) {
        float bb = b2[tx * 8 + j];
#pragma unroll
        for (int i = 0; i < 4; i++) h2s[ty * 4 + i][tx * 8 + j] = acc[i][j] + bb;
    }
    for (int idx = tid; idx < 9 * 128; idx += 256) wcs[idx / 128][idx & 127] = Wc[idx];
    if (tid < 9) bcs[tid] = bc[tid];
    __syncthreads();
    const int r = tid & 63, tg0 = tid >> 6;
    for (int tag = tg0; tag < 9; tag += 4) {
        float s0 = 0, s1 = 0, s2 = 0, s3 = 0;
#pragma unroll
        for (int kk = 0; kk < 32; kk++) {
            float4 hv = *(const float4*)&h2s[r][kk * 4];
            float4 wv = *(const float4*)&wcs[tag][kk * 4];
            s0 += hv.x * wv.x; s1 += hv.y * wv.y;
            s2 += hv.z * wv.z; s3 += hv.w * wv.w;
        }
        em[(size_t)(m0 + r) * NT + tag] = (s0 + s1) + (s2 + s3) + bcs[tag];
    }
}

__global__ __launch_bounds__(64) void viterbi(
    const float* __restrict__ em, const float* __restrict__ startT,
    const float* __restrict__ endT, const float* __restrict__ trans,
    int* __restrict__ out)
{
    const int b = blockIdx.x, j = threadIdx.x;
    __shared__ int hist[511][9];
    __shared__ int tags[512];
    const float* E = em + (size_t)b * 512 * NT;
    const int jj = (j < 9) ? j : 0;
    float sc[9], tc[9];
#pragma unroll
    for (int i = 0; i < 9; i++) sc[i] = startT[i] + E[i];
#pragma unroll
    for (int i = 0; i < 9; i++) tc[i] = trans[i * 9 + jj];
    float e_cur = E[9 + jj];
    for (int s = 1; s < 512; ++s) {
        float e_nxt = (s < 511) ? E[(size_t)(s + 1) * 9 + jj] : 0.f;
        float best = -3.0e38f;
        int bi = 0;
#pragma unroll
        for (int i = 0; i < 9; i++) {
            float v = (sc[i] + tc[i]) + e_cur;
            if (v > best) { best = v; bi = i; }
        }
        if (j < 9) hist[s - 1][j] = bi;
#pragma unroll
        for (int i = 0; i < 9; i++) sc[i] = __shfl(best, i);
        e_cur = e_nxt;
    }
    __syncthreads();
#pragma unroll
    for (int i = 0; i < 9; i++) sc[i] += endT[i];
    float best = -3.0e38f;
    int last = 0;
#pragma unroll
    for (int i = 0; i < 9; i++)
        if (sc[i] > best) { best = sc[i]; last = i; }
    if (j == 0) {
        tags[511] = last;
        int tg = last;
        for (int s = 510; s >= 0; --s) { tg = hist[s][tg]; tags[s] = tg; }
    }
    __syncthreads();
    for (int s = j; s < 512; s += 64) out[(size_t)b * 512 + s] = tags[s];
}

__global__ void fill_out(int* out, int n, int v)
{
    int i = blockIdx.x * 256 + threadIdx.x;
    if (i < n) out[i] = v;
}

// -----------------------------------------------------------------------------------
extern "C" void kernel_launch(void* const* d_in, const int* in_sizes, int n_in,
                              void* d_out, int out_size, void* d_ws, size_t ws_size,
                              hipStream_t stream)
{
    const float* bert = (const float*)d_in[0];
    const float* WihF = (const float*)d_in[2];
    const float* WhhF = (const float*)d_in[3];
    const float* bihF = (const float*)d_in[4];
    const float* bhhF = (const float*)d_in[5];
    const float* WihB = (const float*)d_in[6];
    const float* WhhB = (const float*)d_in[7];
    const float* bihB = (const float*)d_in[8];
    const float* bhhB = (const float*)d_in[9];
    const float* W1 = (const float*)d_in[10];
    const float* b1 = (const float*)d_in[11];
    const float* W2 = (const float*)d_in[12];
    const float* b2 = (const float*)d_in[13];
    const float* Wc = (const float*)d_in[14];
    const float* bc = (const float*)d_in[15];
    const float* stT = (const float*)d_in[16];
    const float* enT = (const float*)d_in[17];
    const float* trs = (const float*)d_in[18];
    int* out = (int*)d_out;

    char* ws = (char*)d_ws;
    float* WT = (float*)ws;
    bool main_ok = false;
    float* hs = nullptr;
    float* h1 = nullptr;
    float* em = nullptr;

    if (ws_size >= MAIN_NEED) {
        float* xgw = (float*)(ws + WT_BYTES);
        hs = (float*)(ws + WT_BYTES + XGW_BYTES);
        h1 = (float*)(ws + WT_BYTES);
        em = (float*)(ws + WT_BYTES + 33554432ull);

        transpose_whh<<<dim3(48, 12, 2), 256, 0, stream>>>(WhhF, WhhB, WT);

        void* args[] = { (void*)&bert, (void*)&WihF, (void*)&WihB,
                         (void*)&bihF, (void*)&bhhF, (void*)&bihB, (void*)&bhhB,
                         (void*)&WT, (void*)&xgw, (void*)&hs };
        hipError_t e = hipLaunchCooperativeKernel(
            (void*)fused_scan, dim3(256), dim3(384), args, 0, stream);
        if (e == hipSuccess) {
            main_ok = true;
        } else {
            (void)hipGetLastError();
        }
    }

    if (!main_ok) {
        int c = 0;
        for (int cc = 2; cc <= 8; cc *= 2) {
            if (ws_size >= WT_BYTES + XGF_BYTES / cc + HS_BYTES) { c = cc; break; }
        }
        if (c == 0) {
            fill_out<<<dim3((out_size + 255) / 256), 256, 0, stream>>>(
                out, out_size, (int)(ws_size >> 20));
            return;
        }
        float* xg = (float*)(ws + WT_BYTES);
        hs = (float*)(ws + WT_BYTES + XGF_BYTES / c);
        h1 = (float*)(ws + WT_BYTES);
        em = (float*)(ws + WT_BYTES + 33554432ull);

        transpose_whh<<<dim3(48, 12, 2), 256, 0, stream>>>(WhhF, WhhB, WT);

        const int Bc = NB / c;
        const int mrows = Bc * 512;
        for (int chunk = 0; chunk < c; ++chunk) {
            int b_base = chunk * Bc;
            gemm_xg<<<dim3(mrows / 128, 24, 2), 256, 0, stream>>>(
                bert, WihF, WihB, bihF, bhhF, bihB, bhhB, xg, b_base, mrows);
            lstm_seq<<<dim3(2 * Bc), 384, 0, stream>>>(xg, WT, hs, b_base, Bc, mrows);
        }
    }

    gemm_h1<<<dim3(256, 4), 256, 0, stream>>>(hs, W1, b1, h1);
    mlp_em<<<dim3(512), 256, 0, stream>>>(h1, W2, b2, Wc, bc, em);
    viterbi<<<dim3(64), 64, 0, stream>>>(em, stT, enT, trs, out);
}